// Round 2
// baseline (629.092 us; speedup 1.0000x reference)
//
#include <hip/hip_runtime.h>

typedef unsigned short u16;
using short8 = __attribute__((ext_vector_type(8))) short;
using f32x4  = __attribute__((ext_vector_type(4))) float;

#define D_MODEL 1024
#define NHEAD 16
#define DKV 64
#define TSEQ 2048
#define BATCH 2

__device__ __forceinline__ float bf2f(u16 u) {
    union { unsigned int i; float f; } c; c.i = ((unsigned int)u) << 16; return c.f;
}
__device__ __forceinline__ u16 f2bf(float f) {
    union { float f; unsigned int i; } c; c.f = f;
    unsigned int x = c.i;
    return (u16)((x + 0x7FFFu + ((x >> 16) & 1u)) >> 16);
}
// load 8 consecutive floats (32B-aligned) -> 8 bf16
__device__ __forceinline__ short8 pack8(const float* p) {
    float4 a = *(const float4*)p;
    float4 b = *(const float4*)(p + 4);
    short8 v;
    v[0] = (short)f2bf(a.x); v[1] = (short)f2bf(a.y);
    v[2] = (short)f2bf(a.z); v[3] = (short)f2bf(a.w);
    v[4] = (short)f2bf(b.x); v[5] = (short)f2bf(b.y);
    v[6] = (short)f2bf(b.z); v[7] = (short)f2bf(b.w);
    return v;
}

// ---------------------------------------------------------------------------
// Kernel 1: fused QKV projection. y = x @ W^T + b  (fp32 in, bf16 ws out as
// [B,H,T,dk]). BM=BN=128, BK=64, 256 threads (4 waves, 2x2 of 64x64).
// ---------------------------------------------------------------------------
__global__ __launch_bounds__(256) void qkv_gemm(
    const float* __restrict__ x,
    const float* __restrict__ Wq, const float* __restrict__ bq,
    const float* __restrict__ Wk, const float* __restrict__ bk,
    const float* __restrict__ Wv, const float* __restrict__ bv,
    u16* __restrict__ qws, u16* __restrict__ kws, u16* __restrict__ vws)
{
    __shared__ __align__(16) u16 Alds[128 * 72];
    __shared__ __align__(16) u16 Blds[128 * 72];

    const float* W; const float* bias; u16* out;
    if (blockIdx.z == 0)      { W = Wq; bias = bq; out = qws; }
    else if (blockIdx.z == 1) { W = Wk; bias = bk; out = kws; }
    else                      { W = Wv; bias = bv; out = vws; }

    const int n0 = blockIdx.x * 128;
    const int m0 = blockIdx.y * 128;
    const int t = threadIdx.x;
    const int wave = t >> 6, lane = t & 63, l15 = lane & 15, quad = lane >> 4;
    const int wm = (wave >> 1) * 64, wn = (wave & 1) * 64;

    f32x4 acc[4][4];
#pragma unroll
    for (int i = 0; i < 4; ++i)
#pragma unroll
        for (int j = 0; j < 4; ++j)
#pragma unroll
            for (int r = 0; r < 4; ++r) acc[i][j][r] = 0.f;

    const int srow = t >> 3, sc8 = (t & 7) * 8;

    for (int kt = 0; kt < 16; ++kt) {
        const int k0 = kt * 64;
#pragma unroll
        for (int p = 0; p < 4; ++p) {
            int row = p * 32 + srow;
            *(short8*)&Alds[row * 72 + sc8] =
                pack8(&x[(size_t)(m0 + row) * 1024 + k0 + sc8]);
            *(short8*)&Blds[row * 72 + sc8] =
                pack8(&W[(size_t)(n0 + row) * 1024 + k0 + sc8]);
        }
        __syncthreads();
#pragma unroll
        for (int ki = 0; ki < 2; ++ki) {
            short8 af[4], bfr[4];
#pragma unroll
            for (int i = 0; i < 4; ++i)
                af[i] = *(const short8*)&Alds[(wm + i * 16 + l15) * 72 + ki * 32 + quad * 8];
#pragma unroll
            for (int j = 0; j < 4; ++j)
                bfr[j] = *(const short8*)&Blds[(wn + j * 16 + l15) * 72 + ki * 32 + quad * 8];
#pragma unroll
            for (int i = 0; i < 4; ++i)
#pragma unroll
                for (int j = 0; j < 4; ++j)
                    acc[i][j] = __builtin_amdgcn_mfma_f32_16x16x32_bf16(af[i], bfr[j], acc[i][j], 0, 0, 0);
        }
        __syncthreads();
    }

    // epilogue: C[m][n] + bias[n] -> ws[b,h,t,d] (bf16)
#pragma unroll
    for (int j = 0; j < 4; ++j) {
        int n = n0 + wn + j * 16 + l15;
        float bb = bias[n];
        int h = n >> 6, d = n & 63;
#pragma unroll
        for (int i = 0; i < 4; ++i)
#pragma unroll
            for (int r = 0; r < 4; ++r) {
                int m = m0 + wm + i * 16 + quad * 4 + r;
                int bidx = m >> 11, tt = m & 2047;
                out[(((size_t)(bidx * NHEAD + h)) * TSEQ + tt) * DKV + d] =
                    f2bf(acc[i][j][r] + bb);
            }
    }
}

// ---------------------------------------------------------------------------
// Kernel 2: flash attention. Block = (64 q-rows, head, batch). 4 waves x 16 q.
// S = QK^T * 0.125 + bias(fp32), online softmax, O += P V. q/k/v from bf16 ws.
// ---------------------------------------------------------------------------
__global__ __launch_bounds__(256) void attn_kernel(
    const u16* __restrict__ qws, const u16* __restrict__ kws, const u16* __restrict__ vws,
    const float* __restrict__ bias, u16* __restrict__ ows)
{
    __shared__ __align__(16) u16 Klds[64 * 72];      // [kc][d]
    __shared__ __align__(16) u16 Vtlds[64 * 72];     // [d][kc] (transposed)
    __shared__ __align__(16) u16 Plds[64 * 72];      // [q_local][kc]
    __shared__ __align__(16) float Bldf[64 * 68];    // [q_local][kc] fp32

    const int qt = blockIdx.x, h = blockIdx.y, b = blockIdx.z;
    const int q0 = qt * 64;
    const int t = threadIdx.x;
    const int wave = t >> 6, lane = t & 63, l15 = lane & 15, quad = lane >> 4;
    const size_t bh = ((size_t)(b * NHEAD + h)) * TSEQ * DKV;

    // Q A-fragments, registers for the whole kernel
    short8 qa0, qa1;
    {
        const u16* qp = qws + bh + (size_t)(q0 + wave * 16 + l15) * DKV;
        qa0 = *(const short8*)(qp + quad * 8);
        qa1 = *(const short8*)(qp + 32 + quad * 8);
    }

    float m_run[4] = {-1e30f, -1e30f, -1e30f, -1e30f};
    float l_run[4] = {0.f, 0.f, 0.f, 0.f};
    f32x4 o_acc[4];
#pragma unroll
    for (int db = 0; db < 4; ++db)
#pragma unroll
        for (int r = 0; r < 4; ++r) o_acc[db][r] = 0.f;

    const float* bias_h = bias + ((size_t)h * TSEQ + q0) * TSEQ;
    const int srow = t >> 3, sc8 = (t & 7) * 8;
    const int trow = t >> 4, tc4 = (t & 15) * 4;
    const int rbase = wave * 16 + quad * 4;

    for (int kt = 0; kt < TSEQ / 64; ++kt) {
        const int kc0 = kt * 64;
        // stage K, V^T (bf16 ws)
#pragma unroll
        for (int p = 0; p < 2; ++p) {
            int row = p * 32 + srow;
            short8 kv = *(const short8*)&kws[bh + (size_t)(kc0 + row) * DKV + sc8];
            *(short8*)&Klds[row * 72 + sc8] = kv;
            short8 vv = *(const short8*)&vws[bh + (size_t)(kc0 + row) * DKV + sc8];
#pragma unroll
            for (int j = 0; j < 8; ++j) Vtlds[(sc8 + j) * 72 + row] = (u16)vv[j];
        }
        // stage bias tile (fp32)
#pragma unroll
        for (int p = 0; p < 4; ++p) {
            int row = p * 16 + trow;
            *(float4*)&Bldf[row * 68 + tc4] =
                *(const float4*)&bias_h[(size_t)row * TSEQ + kc0 + tc4];
        }
        __syncthreads();

        // S = Q K^T
        f32x4 s[4];
#pragma unroll
        for (int cb = 0; cb < 4; ++cb)
#pragma unroll
            for (int r = 0; r < 4; ++r) s[cb][r] = 0.f;
#pragma unroll
        for (int cb = 0; cb < 4; ++cb) {
            short8 kb0 = *(const short8*)&Klds[(cb * 16 + l15) * 72 + quad * 8];
            short8 kb1 = *(const short8*)&Klds[(cb * 16 + l15) * 72 + 32 + quad * 8];
            s[cb] = __builtin_amdgcn_mfma_f32_16x16x32_bf16(qa0, kb0, s[cb], 0, 0, 0);
            s[cb] = __builtin_amdgcn_mfma_f32_16x16x32_bf16(qa1, kb1, s[cb], 0, 0, 0);
        }
        // scale + bias
#pragma unroll
        for (int cb = 0; cb < 4; ++cb)
#pragma unroll
            for (int r = 0; r < 4; ++r)
                s[cb][r] = s[cb][r] * 0.125f + Bldf[(rbase + r) * 68 + cb * 16 + l15];

        // online softmax: rows live in 16-lane groups (same quad)
        float alpha[4], rs[4];
#pragma unroll
        for (int r = 0; r < 4; ++r) {
            float m = fmaxf(fmaxf(s[0][r], s[1][r]), fmaxf(s[2][r], s[3][r]));
            m = fmaxf(m, __shfl_xor(m, 1));
            m = fmaxf(m, __shfl_xor(m, 2));
            m = fmaxf(m, __shfl_xor(m, 4));
            m = fmaxf(m, __shfl_xor(m, 8));
            float mn = fmaxf(m_run[r], m);
            alpha[r] = __expf(m_run[r] - mn);
            m_run[r] = mn;
            rs[r] = 0.f;
        }
#pragma unroll
        for (int cb = 0; cb < 4; ++cb)
#pragma unroll
            for (int r = 0; r < 4; ++r) {
                float p = __expf(s[cb][r] - m_run[r]);
                s[cb][r] = p;
                rs[r] += p;
            }
#pragma unroll
        for (int r = 0; r < 4; ++r) {
            rs[r] += __shfl_xor(rs[r], 1);
            rs[r] += __shfl_xor(rs[r], 2);
            rs[r] += __shfl_xor(rs[r], 4);
            rs[r] += __shfl_xor(rs[r], 8);
            l_run[r] = l_run[r] * alpha[r] + rs[r];
        }
#pragma unroll
        for (int db = 0; db < 4; ++db)
#pragma unroll
            for (int r = 0; r < 4; ++r) o_acc[db][r] *= alpha[r];

        // P: C-layout -> LDS -> A-layout
#pragma unroll
        for (int cb = 0; cb < 4; ++cb)
#pragma unroll
            for (int r = 0; r < 4; ++r)
                Plds[(rbase + r) * 72 + cb * 16 + l15] = f2bf(s[cb][r]);
        __syncthreads();

        short8 pa0 = *(const short8*)&Plds[(wave * 16 + l15) * 72 + quad * 8];
        short8 pa1 = *(const short8*)&Plds[(wave * 16 + l15) * 72 + 32 + quad * 8];
#pragma unroll
        for (int db = 0; db < 4; ++db) {
            short8 vb0 = *(const short8*)&Vtlds[(db * 16 + l15) * 72 + quad * 8];
            short8 vb1 = *(const short8*)&Vtlds[(db * 16 + l15) * 72 + 32 + quad * 8];
            o_acc[db] = __builtin_amdgcn_mfma_f32_16x16x32_bf16(pa0, vb0, o_acc[db], 0, 0, 0);
            o_acc[db] = __builtin_amdgcn_mfma_f32_16x16x32_bf16(pa1, vb1, o_acc[db], 0, 0, 0);
        }
        __syncthreads();
    }

    // epilogue: O /= l, store [B,H,T,dk] bf16 ws
#pragma unroll
    for (int r = 0; r < 4; ++r) {
        float inv = 1.f / l_run[r];
        int row = q0 + wave * 16 + quad * 4 + r;
#pragma unroll
        for (int db = 0; db < 4; ++db)
            ows[bh + (size_t)row * DKV + db * 16 + l15] = f2bf(o_acc[db][r] * inv);
    }
}

// ---------------------------------------------------------------------------
// Kernel 3: output projection. out(fp32) = O(bf16 ws) @ Wo^T(fp32) + bo.
// A read head-wise from [B,H,T,dk] ws (BK=64 == one head).
// ---------------------------------------------------------------------------
__global__ __launch_bounds__(256) void out_gemm(
    const u16* __restrict__ ows, const float* __restrict__ Wo, const float* __restrict__ bo,
    float* __restrict__ out)
{
    __shared__ __align__(16) u16 Alds[128 * 72];
    __shared__ __align__(16) u16 Blds[128 * 72];

    const int n0 = blockIdx.x * 128;
    const int m0 = blockIdx.y * 128;
    const int t = threadIdx.x;
    const int wave = t >> 6, lane = t & 63, l15 = lane & 15, quad = lane >> 4;
    const int wm = (wave >> 1) * 64, wn = (wave & 1) * 64;

    f32x4 acc[4][4];
#pragma unroll
    for (int i = 0; i < 4; ++i)
#pragma unroll
        for (int j = 0; j < 4; ++j)
#pragma unroll
            for (int r = 0; r < 4; ++r) acc[i][j][r] = 0.f;

    const int srow = t >> 3, sc8 = (t & 7) * 8;

    for (int kt = 0; kt < 16; ++kt) {
        const int k0 = kt * 64;
#pragma unroll
        for (int p = 0; p < 4; ++p) {
            int row = p * 32 + srow;
            int m = m0 + row;
            int bidx = m >> 11, tt = m & 2047;
            *(short8*)&Alds[row * 72 + sc8] =
                *(const short8*)&ows[(((size_t)(bidx * NHEAD + kt)) * TSEQ + tt) * DKV + sc8];
            *(short8*)&Blds[row * 72 + sc8] =
                pack8(&Wo[(size_t)(n0 + row) * 1024 + k0 + sc8]);
        }
        __syncthreads();
#pragma unroll
        for (int ki = 0; ki < 2; ++ki) {
            short8 af[4], bfr[4];
#pragma unroll
            for (int i = 0; i < 4; ++i)
                af[i] = *(const short8*)&Alds[(wm + i * 16 + l15) * 72 + ki * 32 + quad * 8];
#pragma unroll
            for (int j = 0; j < 4; ++j)
                bfr[j] = *(const short8*)&Blds[(wn + j * 16 + l15) * 72 + ki * 32 + quad * 8];
#pragma unroll
            for (int i = 0; i < 4; ++i)
#pragma unroll
                for (int j = 0; j < 4; ++j)
                    acc[i][j] = __builtin_amdgcn_mfma_f32_16x16x32_bf16(af[i], bfr[j], acc[i][j], 0, 0, 0);
        }
        __syncthreads();
    }

#pragma unroll
    for (int j = 0; j < 4; ++j) {
        int n = n0 + wn + j * 16 + l15;
        float bb = bo[n];
#pragma unroll
        for (int i = 0; i < 4; ++i)
#pragma unroll
            for (int r = 0; r < 4; ++r) {
                int m = m0 + wm + i * 16 + quad * 4 + r;
                out[(size_t)m * 1024 + n] = acc[i][j][r] + bb;
            }
    }
}

extern "C" void kernel_launch(void* const* d_in, const int* in_sizes, int n_in,
                              void* d_out, int out_size, void* d_ws, size_t ws_size,
                              hipStream_t stream)
{
    const float* x  = (const float*)d_in[0];
    const float* ab = (const float*)d_in[1];
    const float* Wq = (const float*)d_in[2];
    const float* bq = (const float*)d_in[3];
    const float* Wk = (const float*)d_in[4];
    const float* bk = (const float*)d_in[5];
    const float* Wv = (const float*)d_in[6];
    const float* bv = (const float*)d_in[7];
    const float* Wo = (const float*)d_in[8];
    const float* bo = (const float*)d_in[9];
    float* out = (float*)d_out;

    const size_t QSZ = (size_t)BATCH * NHEAD * TSEQ * DKV;  // 4.19M elems (bf16)
    u16* qws = (u16*)d_ws;
    u16* kws = qws + QSZ;
    u16* vws = kws + QSZ;
    u16* osw = vws + QSZ;

    qkv_gemm<<<dim3(8, 32, 3), 256, 0, stream>>>(x, Wq, bq, Wk, bk, Wv, bv, qws, kws, vws);
    attn_kernel<<<dim3(TSEQ / 64, NHEAD, BATCH), 256, 0, stream>>>(qws, kws, vws, ab, osw);
    out_gemm<<<dim3(8, 32, 1), 256, 0, stream>>>(osw, Wo, bo, out);
}

// Round 3
// 505.915 us; speedup vs baseline: 1.2435x; 1.2435x over previous
//
#include <hip/hip_runtime.h>

typedef unsigned short u16;
typedef unsigned int u32;
using short8 = __attribute__((ext_vector_type(8))) short;
using f32x4  = __attribute__((ext_vector_type(4))) float;

#define D_MODEL 1024
#define NHEAD 16
#define DKV 64
#define TSEQ 2048
#define BATCH 2
#define L2E 1.44269504f
#define CSHIFT 12.0f

__device__ __forceinline__ u16 f2bf(float f) {      // RNE
    union { float f; u32 i; } c; c.f = f;
    u32 x = c.i;
    return (u16)((x + 0x7FFFu + ((x >> 16) & 1u)) >> 16);
}
__device__ __forceinline__ u16 f2bf_fast(float f) { // round-half-up (P only)
    union { float f; u32 i; } c; c.f = f;
    return (u16)((c.i + 0x8000u) >> 16);
}

// ---------------------------------------------------------------------------
// Kernel 0: fp32 -> bf16 prep. Converts x (4.19M) + Wq/Wk/Wv/Wo (1.05M each)
// into ws, laid out contiguously: [xbf | wq | wk | wv | wo]. Exact coverage.
// ---------------------------------------------------------------------------
__global__ __launch_bounds__(256) void prep_cvt(
    const float* __restrict__ x,  const float* __restrict__ Wq,
    const float* __restrict__ Wk, const float* __restrict__ Wv,
    const float* __restrict__ Wo, u16* __restrict__ dst)
{
    size_t e = ((size_t)blockIdx.x * 256 + threadIdx.x) * 8;
    const float* src; size_t off;
    if (e < 4194304u)      { src = x;  off = e; }
    else if (e < 5242880u) { src = Wq; off = e - 4194304u; }
    else if (e < 6291456u) { src = Wk; off = e - 5242880u; }
    else if (e < 7340032u) { src = Wv; off = e - 6291456u; }
    else                   { src = Wo; off = e - 7340032u; }
    float4 a = *(const float4*)(src + off);
    float4 b = *(const float4*)(src + off + 4);
    short8 v;
    v[0] = (short)f2bf(a.x); v[1] = (short)f2bf(a.y);
    v[2] = (short)f2bf(a.z); v[3] = (short)f2bf(a.w);
    v[4] = (short)f2bf(b.x); v[5] = (short)f2bf(b.y);
    v[6] = (short)f2bf(b.z); v[7] = (short)f2bf(b.w);
    *(short8*)(dst + e) = v;
}

// ---------------------------------------------------------------------------
// Kernel 1: fused QKV projection from bf16 x/W. Grid = 768 1-D, XCD-swizzled
// so each XCD keeps one z-phase working set (x-slab + W) in its 4MB L2.
// ---------------------------------------------------------------------------
__global__ __launch_bounds__(256) void qkv_gemm(
    const u16* __restrict__ xbf, const u16* __restrict__ wbf,
    const float* __restrict__ bq, const float* __restrict__ bk,
    const float* __restrict__ bv, u16* __restrict__ qkv)
{
    __shared__ __align__(16) u16 Alds[128 * 72];
    __shared__ __align__(16) u16 Blds[128 * 72];

    const int fid = blockIdx.x;
    const int xcd = fid & 7, ii = fid >> 3;       // ii in 0..95
    const int z = ii >> 5, r2 = ii & 31;
    const int nb = r2 & 7, mb = xcd * 4 + (r2 >> 3);
    const int n0 = nb * 128, m0 = mb * 128;
    const u16* W = wbf + (size_t)z * 1048576;
    const float* bias = (z == 0) ? bq : (z == 1) ? bk : bv;
    u16* out = qkv + (size_t)z * 4194304;

    const int t = threadIdx.x;
    const int wave = t >> 6, lane = t & 63, l15 = lane & 15, quad = lane >> 4;
    const int wm = (wave >> 1) * 64, wn = (wave & 1) * 64;

    f32x4 acc[4][4];
#pragma unroll
    for (int i = 0; i < 4; ++i)
#pragma unroll
        for (int j = 0; j < 4; ++j)
#pragma unroll
            for (int r = 0; r < 4; ++r) acc[i][j][r] = 0.f;

    const int srow = t >> 3, sc8 = (t & 7) * 8;

    for (int kt = 0; kt < 16; ++kt) {
        const int k0 = kt * 64;
#pragma unroll
        for (int p = 0; p < 4; ++p) {
            int row = p * 32 + srow;
            *(short8*)&Alds[row * 72 + sc8] =
                *(const short8*)&xbf[(size_t)(m0 + row) * 1024 + k0 + sc8];
            *(short8*)&Blds[row * 72 + sc8] =
                *(const short8*)&W[(size_t)(n0 + row) * 1024 + k0 + sc8];
        }
        __syncthreads();
#pragma unroll
        for (int ki = 0; ki < 2; ++ki) {
            short8 af[4], bfr[4];
#pragma unroll
            for (int i = 0; i < 4; ++i)
                af[i] = *(const short8*)&Alds[(wm + i * 16 + l15) * 72 + ki * 32 + quad * 8];
#pragma unroll
            for (int j = 0; j < 4; ++j)
                bfr[j] = *(const short8*)&Blds[(wn + j * 16 + l15) * 72 + ki * 32 + quad * 8];
#pragma unroll
            for (int i = 0; i < 4; ++i)
#pragma unroll
                for (int j = 0; j < 4; ++j)
                    acc[i][j] = __builtin_amdgcn_mfma_f32_16x16x32_bf16(af[i], bfr[j], acc[i][j], 0, 0, 0);
        }
        __syncthreads();
    }

#pragma unroll
    for (int j = 0; j < 4; ++j) {
        int n = n0 + wn + j * 16 + l15;
        float bb = bias[n];
        int h = n >> 6, d = n & 63;
#pragma unroll
        for (int i = 0; i < 4; ++i)
#pragma unroll
            for (int r = 0; r < 4; ++r) {
                int m = m0 + wm + i * 16 + quad * 4 + r;
                int bidx = m >> 11, tt = m & 2047;
                out[(((size_t)(bidx * NHEAD + h)) * TSEQ + tt) * DKV + d] =
                    f2bf(acc[i][j][r] + bb);
            }
    }
}

// ---------------------------------------------------------------------------
// Kernel 2: flash attention, fixed-shift softmax (exact: constant shift
// cancels in softmax). No shuffles/rescale in loop. Bias global->reg.
// V staged transposed with XOR-swizzled packed u32 writes (conflict-free).
// Vt double-buffered -> 2 barriers/tile, race-free.
// ---------------------------------------------------------------------------
__global__ __launch_bounds__(256) void attn_kernel(
    const u16* __restrict__ qws, const u16* __restrict__ kws, const u16* __restrict__ vws,
    const float* __restrict__ bias, u16* __restrict__ ows)
{
    __shared__ __align__(16) u16 Klds[64 * 72];
    __shared__ __align__(16) u16 Vt[2][64 * 72];
    __shared__ __align__(16) u16 Plds[64 * 72];

    const int fid = blockIdx.x;
    const int xcd = fid & 7, ii = fid >> 3;        // ii in 0..127
    const int bh = xcd * 4 + (ii >> 5);            // same (b,h) grouped per XCD
    const int qt = ii & 31;
    const int h = bh & 15;
    const int q0 = qt * 64;
    const int t = threadIdx.x;
    const int wave = t >> 6, lane = t & 63, l15 = lane & 15, quad = lane >> 4;
    const size_t bhoff = (size_t)bh * TSEQ * DKV;  // bh == b*NHEAD+h

    // Q A-fragments, loop-invariant in registers
    short8 qa0, qa1;
    {
        const u16* qp = qws + bhoff + (size_t)(q0 + wave * 16 + l15) * DKV;
        qa0 = *(const short8*)(qp + quad * 8);
        qa1 = *(const short8*)(qp + 32 + quad * 8);
    }

    float l_run[4] = {0.f, 0.f, 0.f, 0.f};
    f32x4 o_acc[4];
#pragma unroll
    for (int db = 0; db < 4; ++db)
#pragma unroll
        for (int r = 0; r < 4; ++r) o_acc[db][r] = 0.f;

    const float* bias_h = bias + ((size_t)h * TSEQ + q0) * TSEQ;
    const int a8 = t & 7, c8 = a8 * 8, rp = t >> 3;
    const int rbase = wave * 16 + quad * 4;

    for (int kt = 0; kt < TSEQ / 64; ++kt) {
        const int kc0 = kt * 64;
        u16* vtb = &Vt[kt & 1][0];

        // bias tile -> registers (C-layout), overlaps staging latency
        float bz[16];
#pragma unroll
        for (int cb = 0; cb < 4; ++cb)
#pragma unroll
            for (int r = 0; r < 4; ++r)
                bz[cb * 4 + r] =
                    bias_h[(size_t)(rbase + r) * TSEQ + kc0 + cb * 16 + l15];

        // stage K (row-major)
        {
            const u16* kp = kws + bhoff + (size_t)(kc0 + rp) * DKV + c8;
            short8 k0 = *(const short8*)kp;
            short8 k1 = *(const short8*)(kp + 32 * DKV);
            *(short8*)&Klds[rp * 72 + c8] = k0;
            *(short8*)&Klds[(rp + 32) * 72 + c8] = k1;
        }
        // stage V transposed: rows (2rp, 2rp+1) packed as u32, 8-blocks XORed
        // by (d>>3) -> conflict-free writes, b128-readable rows
        {
            const u16* vp = vws + bhoff + (size_t)(kc0 + 2 * rp) * DKV + c8;
            short8 v0 = *(const short8*)vp;
            short8 v1 = *(const short8*)(vp + DKV);
            int bk = rp >> 2;
            int kcl = (2 * rp) & 7;
#pragma unroll
            for (int j = 0; j < 8; ++j) {
                int d = c8 + j;
                u32 val = ((u32)(u16)v0[j]) | (((u32)(u16)v1[j]) << 16);
                *(u32*)&vtb[d * 72 + ((bk ^ a8) * 8) + kcl] = val;
            }
        }
        __syncthreads();

        // S = Q K^T
        f32x4 s[4];
#pragma unroll
        for (int cb = 0; cb < 4; ++cb)
#pragma unroll
            for (int r = 0; r < 4; ++r) s[cb][r] = 0.f;
#pragma unroll
        for (int cb = 0; cb < 4; ++cb) {
            const u16* kr = &Klds[(cb * 16 + l15) * 72 + quad * 8];
            short8 kb0 = *(const short8*)kr;
            short8 kb1 = *(const short8*)(kr + 32);
            s[cb] = __builtin_amdgcn_mfma_f32_16x16x32_bf16(qa0, kb0, s[cb], 0, 0, 0);
            s[cb] = __builtin_amdgcn_mfma_f32_16x16x32_bf16(qa1, kb1, s[cb], 0, 0, 0);
        }

        // p = exp(s/8 + bias - C) via exp2; accumulate l; pack P to LDS
#pragma unroll
        for (int cb = 0; cb < 4; ++cb)
#pragma unroll
            for (int r = 0; r < 4; ++r) {
                float arg = fmaf(s[cb][r], 0.125f * L2E,
                                 fmaf(bz[cb * 4 + r], L2E, -CSHIFT * L2E));
                float p = exp2f(fminf(arg, 43.f));
                l_run[r] += p;
                Plds[(rbase + r) * 72 + cb * 16 + l15] = f2bf_fast(p);
            }
        __syncthreads();

        // PV: O += P V  (V frags from swizzled Vt, double-buffered)
        {
            const u16* pr = &Plds[(wave * 16 + l15) * 72 + quad * 8];
            short8 pa0 = *(const short8*)pr;
            short8 pa1 = *(const short8*)(pr + 32);
#pragma unroll
            for (int db = 0; db < 4; ++db) {
                int d = db * 16 + l15;
                int sw = (d >> 3) & 7;
                const u16* vr = &vtb[d * 72];
                short8 vb0 = *(const short8*)(vr + ((quad ^ sw) * 8));
                short8 vb1 = *(const short8*)(vr + (((4 + quad) ^ sw) * 8));
                o_acc[db] = __builtin_amdgcn_mfma_f32_16x16x32_bf16(pa0, vb0, o_acc[db], 0, 0, 0);
                o_acc[db] = __builtin_amdgcn_mfma_f32_16x16x32_bf16(pa1, vb1, o_acc[db], 0, 0, 0);
            }
        }
    }

    // one-time l reduction across the 16-lane row group
#pragma unroll
    for (int r = 0; r < 4; ++r) {
        float v = l_run[r];
        v += __shfl_xor(v, 1);
        v += __shfl_xor(v, 2);
        v += __shfl_xor(v, 4);
        v += __shfl_xor(v, 8);
        l_run[r] = v;
    }
#pragma unroll
    for (int r = 0; r < 4; ++r) {
        float inv = 1.f / l_run[r];
        int row = q0 + rbase + r;
#pragma unroll
        for (int db = 0; db < 4; ++db)
            ows[bhoff + (size_t)row * DKV + db * 16 + l15] = f2bf(o_acc[db][r] * inv);
    }
}

// ---------------------------------------------------------------------------
// Kernel 3: output projection, bf16 Wo from prep. Grid 256 1-D, XCD-swizzled.
// ---------------------------------------------------------------------------
__global__ __launch_bounds__(256) void out_gemm(
    const u16* __restrict__ ows, const u16* __restrict__ wobf,
    const float* __restrict__ bo, float* __restrict__ out)
{
    __shared__ __align__(16) u16 Alds[128 * 72];
    __shared__ __align__(16) u16 Blds[128 * 72];

    const int fid = blockIdx.x;
    const int xcd = fid & 7, ii = fid >> 3;     // ii in 0..31
    const int nb = ii & 7, mb = xcd * 4 + (ii >> 3);
    const int n0 = nb * 128, m0 = mb * 128;

    const int t = threadIdx.x;
    const int wave = t >> 6, lane = t & 63, l15 = lane & 15, quad = lane >> 4;
    const int wm = (wave >> 1) * 64, wn = (wave & 1) * 64;

    f32x4 acc[4][4];
#pragma unroll
    for (int i = 0; i < 4; ++i)
#pragma unroll
        for (int j = 0; j < 4; ++j)
#pragma unroll
            for (int r = 0; r < 4; ++r) acc[i][j][r] = 0.f;

    const int srow = t >> 3, sc8 = (t & 7) * 8;

    for (int kt = 0; kt < 16; ++kt) {
        const int k0 = kt * 64;
#pragma unroll
        for (int p = 0; p < 4; ++p) {
            int row = p * 32 + srow;
            int m = m0 + row;
            int bidx = m >> 11, tt = m & 2047;
            *(short8*)&Alds[row * 72 + sc8] =
                *(const short8*)&ows[(((size_t)(bidx * NHEAD + kt)) * TSEQ + tt) * DKV + sc8];
            *(short8*)&Blds[row * 72 + sc8] =
                *(const short8*)&wobf[(size_t)(n0 + row) * 1024 + k0 + sc8];
        }
        __syncthreads();
#pragma unroll
        for (int ki = 0; ki < 2; ++ki) {
            short8 af[4], bfr[4];
#pragma unroll
            for (int i = 0; i < 4; ++i)
                af[i] = *(const short8*)&Alds[(wm + i * 16 + l15) * 72 + ki * 32 + quad * 8];
#pragma unroll
            for (int j = 0; j < 4; ++j)
                bfr[j] = *(const short8*)&Blds[(wn + j * 16 + l15) * 72 + ki * 32 + quad * 8];
#pragma unroll
            for (int i = 0; i < 4; ++i)
#pragma unroll
                for (int j = 0; j < 4; ++j)
                    acc[i][j] = __builtin_amdgcn_mfma_f32_16x16x32_bf16(af[i], bfr[j], acc[i][j], 0, 0, 0);
        }
        __syncthreads();
    }

#pragma unroll
    for (int j = 0; j < 4; ++j) {
        int n = n0 + wn + j * 16 + l15;
        float bb = bo[n];
#pragma unroll
        for (int i = 0; i < 4; ++i)
#pragma unroll
            for (int r = 0; r < 4; ++r) {
                int m = m0 + wm + i * 16 + quad * 4 + r;
                out[(size_t)m * 1024 + n] = acc[i][j][r] + bb;
            }
    }
}

extern "C" void kernel_launch(void* const* d_in, const int* in_sizes, int n_in,
                              void* d_out, int out_size, void* d_ws, size_t ws_size,
                              hipStream_t stream)
{
    const float* x  = (const float*)d_in[0];
    const float* ab = (const float*)d_in[1];
    const float* Wq = (const float*)d_in[2];
    const float* bq = (const float*)d_in[3];
    const float* Wk = (const float*)d_in[4];
    const float* bk = (const float*)d_in[5];
    const float* Wv = (const float*)d_in[6];
    const float* bv = (const float*)d_in[7];
    const float* Wo = (const float*)d_in[8];
    const float* bo = (const float*)d_in[9];
    float* out = (float*)d_out;

    u16* wsu = (u16*)d_ws;
    // ws layout (u16 elems): [0 xbf 4.19M | 4.19M wq,wk,wv,wo 4x1.05M |
    //                         8.39M q,k,v 3x4.19M | 20.97M o 4.19M]  = 48 MB
    const size_t WBF = 4194304;
    const size_t QKV = 8388608;
    const size_t OWS = 20971520;
    const size_t QSZ = 4194304;

    prep_cvt<<<4096, 256, 0, stream>>>(x, Wq, Wk, Wv, Wo, wsu);
    qkv_gemm<<<768, 256, 0, stream>>>(wsu, wsu + WBF, bq, bk, bv, wsu + QKV);
    attn_kernel<<<1024, 256, 0, stream>>>(wsu + QKV, wsu + QKV + QSZ,
                                          wsu + QKV + 2 * QSZ, ab, wsu + OWS);
    out_gemm<<<256, 256, 0, stream>>>(wsu + OWS, wsu + WBF + 3 * 1048576, bo, out);
}